// Round 6
// baseline (510.949 us; speedup 1.0000x reference)
//
#include <hip/hip_runtime.h>

#define T_TOKENS 2048
#define HIDDEN   2048
#define NEXPERT  32
#define TOPK     4
#define INTER    768
#define GUF      (2*INTER)         /* 1536 */
#define NPAIRS   (T_TOKENS*TOPK)   /* 8192 */
#define BM       128
#define BK       32
#define MT_MAX   95
#define NT1      6                 /* 1536/256 */
#define NT2      8                 /* 2048/256 */
#define NK1      (HIDDEN/BK)       /* 64 */
#define NK2      (INTER/BK)        /* 24 */

typedef short  bh8 __attribute__((ext_vector_type(8)));   // 8 bf16
typedef float  fx4 __attribute__((ext_vector_type(4)));

#define AS1 __attribute__((address_space(1)))
#define AS3 __attribute__((address_space(3)))

__device__ __forceinline__ void gload_lds16(const void* g, const void* lds_generic){
    __builtin_amdgcn_global_load_lds(
        (const AS1 void*)(unsigned long long)g,
        (AS3 void*)(unsigned int)(unsigned long long)lds_generic,
        16, 0, 0);
}

// pack two f32 -> two bf16 (round-half-up); result shorts [a(lo), b(hi)]
__device__ __forceinline__ unsigned int pack2bf(float a, float b){
    unsigned ua = __float_as_uint(a) + 0x8000u;
    unsigned ub = __float_as_uint(b) + 0x8000u;
    return __builtin_amdgcn_perm(ub, ua, 0x07060302u);
}
__device__ __forceinline__ unsigned short f2bfu(float f){
    return (unsigned short)((__float_as_uint(f) + 0x8000u) >> 16);
}
__device__ __forceinline__ float bf2f(unsigned short s){
    return __uint_as_float(((unsigned)s)<<16);
}

/* ---------------- x -> bf16 ---------------- */
__global__ void cvt_x_k(const float* __restrict__ x, unsigned short* __restrict__ xb){
    int i = (blockIdx.x*256 + threadIdx.x)*8;
    float4 a = *(const float4*)(x+i);
    float4 b = *(const float4*)(x+i+4);
    uint4 o;
    o.x = pack2bf(a.x,a.y); o.y = pack2bf(a.z,a.w);
    o.z = pack2bf(b.x,b.y); o.w = pack2bf(b.z,b.w);
    *(uint4*)(xb+i) = o;
}

/* ---------------- router ---------------- */
__global__ void router_k(const float* __restrict__ x, const float* __restrict__ gate,
                         int* __restrict__ topk_id, float* __restrict__ topk_w,
                         int* __restrict__ counts){
    const int t = blockIdx.x;
    const int l = threadIdx.x;
    const float* xr = x + (size_t)t*HIDDEN;
    float acc[NEXPERT];
#pragma unroll
    for (int e=0;e<NEXPERT;e++) acc[e]=0.f;
    for (int d=l; d<HIDDEN; d+=64){
        float xv = xr[d];
        const float4* g4 = (const float4*)(gate + (size_t)d*NEXPERT);
#pragma unroll
        for (int i=0;i<8;i++){
            float4 g = g4[i];
            acc[i*4+0] += xv*g.x; acc[i*4+1] += xv*g.y;
            acc[i*4+2] += xv*g.z; acc[i*4+3] += xv*g.w;
        }
    }
#pragma unroll
    for (int e=0;e<NEXPERT;e++){
#pragma unroll
        for (int m=1;m<64;m<<=1) acc[e] += __shfl_xor(acc[e], m, 64);
    }
    int ids[TOPK]; float lv[TOPK];
#pragma unroll
    for (int k=0;k<TOPK;k++){
        float m=-1e30f; int mi=0;
#pragma unroll
        for (int e=0;e<NEXPERT;e++){ if (acc[e]>m){ m=acc[e]; mi=e; } }
        ids[k]=mi; lv[k]=m; acc[mi]=-1e30f;
    }
    float ex[TOPK]; float s=0.f;
#pragma unroll
    for (int k=0;k<TOPK;k++){ ex[k]=__expf(lv[k]-lv[0]); s+=ex[k]; }
    if (l==0){
        float inv = 1.f/s;
#pragma unroll
        for (int k=0;k<TOPK;k++){
            topk_id[t*TOPK+k]=ids[k];
            topk_w[t*TOPK+k]=ex[k]*inv;
            atomicAdd(&counts[ids[k]],1);
        }
    }
}

/* ---------------- schedule ---------------- */
__global__ void sched_k(const int* __restrict__ counts, int* __restrict__ offs,
                        int* __restrict__ cursors, int* __restrict__ nmt,
                        int* __restrict__ te, int* __restrict__ tr0, int* __restrict__ trn){
    if (threadIdx.x==0 && blockIdx.x==0){
        int tot=0, nm=0;
        for (int e=0;e<NEXPERT;e++){
            int c = counts[e];
            offs[e]=tot; cursors[e]=tot;
            for (int s=0;s<c;s+=BM){
                te[nm]=e; tr0[nm]=tot+s; trn[nm]=(c-s)<BM?(c-s):BM; nm++;
            }
            tot+=c;
        }
        *nmt = nm;
    }
}

/* ---------------- scatter ---------------- */
__global__ void scatter_k(const int* __restrict__ topk_id, const float* __restrict__ topk_w,
                          int* __restrict__ cursors, int* __restrict__ pair_tok,
                          float* __restrict__ pair_w){
    int g = blockIdx.x*256 + threadIdx.x;
    int e = topk_id[g];
    float w = topk_w[g];
    int pos = atomicAdd(&cursors[e],1);
    pair_tok[pos] = g>>2;
    pair_w[pos]  = w;
}

/* tile-id decode: bijective XCD-chunked swizzle, mt innermost */
#define TILE_DECODE()                                              \
    const int nwg = gridDim.x;                                     \
    const int q = nwg>>3, r = nwg&7;                               \
    const int xcd = blockIdx.x & 7, bidx = blockIdx.x >> 3;        \
    const int L = (xcd<r ? xcd*(q+1) : r*(q+1)+(xcd-r)*q) + bidx;  \
    const int mt = L % MT_MAX, nt = L / MT_MAX;                    \
    if (mt >= *nmt) return;                                        \
    const int e = te[mt], row0 = tr0[mt], rows = trn[mt];

/* ============== grouped GEMM1: xb(bf16) x gup(f32) -> gu(bf16, raw) ==============
   BN=256 contiguous cols; 512 thr (8 waves: wr=w&3 row-group, wc=w>>2 col-group). */
__global__ __launch_bounds__(512,4) void gemm1_k(
        const unsigned short* __restrict__ xb, const float* __restrict__ gup,
        const int* __restrict__ nmt, const int* __restrict__ te,
        const int* __restrict__ tr0, const int* __restrict__ trn,
        const int* __restrict__ pair_tok,
        unsigned short* __restrict__ gu){
    __shared__ __align__(16) unsigned short As[2][BM*32];   // 2 x 8KB
    __shared__ __align__(16) unsigned short Bs[2][256*40];  // 2 x 20KB, pitch 80B/col
    __shared__ int s_tok[BM];

    TILE_DECODE()
    const int n0 = nt*256;

    const int t = threadIdx.x;
    if (t < BM){
        int p = row0 + t; if (p > NPAIRS-1) p = NPAIRS-1;
        s_tok[t] = pair_tok[p];
    }
    __syncthreads();

    const int w = t>>6, lane = t&63;
    const int l15 = lane & 15, kb = lane >> 4;
    const int wr = w & 3, wc = w >> 2;
    const int sA = (l15>>1)&3;

    // A DMA: wave w stages rows w*16..w*16+15 (1 inst/step)
    const int arow = w*16 + (lane>>2);
    const int ck0 = (lane&3) ^ ((lane>>3)&3);
    const unsigned short* asrc = xb + (size_t)s_tok[arow]*HIDDEN + ck0*8;

    // B: thread stages cols 2cp,2cp+1 x 8 k-rows (kh*8..+7); 512B-coalesced float2 loads
    const int cp = t & 127, kh = t >> 7;
    const float* bsrc = gup + (size_t)e*HIDDEN*GUF + (size_t)kh*8*GUF + (n0 + 2*cp);
    const unsigned wb0 = (unsigned)((2*cp)*80 + ((kh ^ (cp&3))<<4));

    fx4 acc[2][8];
#pragma unroll
    for (int i=0;i<2;i++)
#pragma unroll
        for (int j=0;j<8;j++) acc[i][j] = (fx4)0.f;

    float2 f0,f1,f2,f3,f4,f5,f6,f7;

#define LOADB1(KS) do{ const float* _bp = bsrc + (size_t)(KS)*BK*GUF;           \
    f0=*(const float2*)(_bp);        f1=*(const float2*)(_bp+GUF);              \
    f2=*(const float2*)(_bp+2*GUF);  f3=*(const float2*)(_bp+3*GUF);            \
    f4=*(const float2*)(_bp+4*GUF);  f5=*(const float2*)(_bp+5*GUF);            \
    f6=*(const float2*)(_bp+6*GUF);  f7=*(const float2*)(_bp+7*GUF); }while(0)

#define WRITEB(BUF) do{ char* _bb = (char*)Bs[BUF];                             \
    uint4 _c0, _c1;                                                             \
    _c0.x=pack2bf(f0.x,f1.x); _c0.y=pack2bf(f2.x,f3.x);                         \
    _c0.z=pack2bf(f4.x,f5.x); _c0.w=pack2bf(f6.x,f7.x);                         \
    _c1.x=pack2bf(f0.y,f1.y); _c1.y=pack2bf(f2.y,f3.y);                         \
    _c1.z=pack2bf(f4.y,f5.y); _c1.w=pack2bf(f6.y,f7.y);                         \
    *(uint4*)(_bb + wb0) = _c0; *(uint4*)(_bb + wb0 + 80) = _c1; }while(0)

#define STAGEA1(KS,BUF) gload_lds16(asrc + (KS)*BK, &As[BUF][(w*16)*32])

#define COMPUTE(BUF) do{                                                        \
    const unsigned short* _Ak = As[BUF];                                        \
    const char* _Bb = (const char*)Bs[BUF];                                     \
    bh8 _a0 = *(const bh8*)(_Ak + (wr*32+l15)*32    + ((kb^sA)<<3));            \
    bh8 _a1 = *(const bh8*)(_Ak + (wr*32+16+l15)*32 + ((kb^sA)<<3));            \
    _Pragma("unroll")                                                           \
    for (int c=0;c<8;c++){                                                      \
        bh8 _b = *(const bh8*)(_Bb + (wc*128 + c*16 + l15)*80 + ((kb^sA)<<4));  \
        acc[0][c] = __builtin_amdgcn_mfma_f32_16x16x32_bf16(_a0,_b,acc[0][c],0,0,0); \
        acc[1][c] = __builtin_amdgcn_mfma_f32_16x16x32_bf16(_a1,_b,acc[1][c],0,0,0); \
    } }while(0)

    // prologue
    STAGEA1(0,0); LOADB1(0);
    __syncthreads();
    WRITEB(0);
    __syncthreads();

    for (int k=0;k<NK1;k++){
        const int kn = k+1;
        if (kn < NK1){ LOADB1(kn); STAGEA1(kn, kn&1); }
        COMPUTE(k&1);
        __syncthreads();
        if (kn < NK1) WRITEB(kn&1);
        __syncthreads();
    }

    // epilogue: raw gu write (silu in separate pass)
    const int rbase = wr*32 + kb*4;
#pragma unroll
    for (int mr=0;mr<2;mr++){
#pragma unroll
        for (int qq=0;qq<4;qq++){
            int row = rbase + mr*16 + qq;
            if (row < rows){
                size_t prow = (size_t)(row0 + row)*GUF + n0 + wc*128 + l15;
#pragma unroll
                for (int c=0;c<8;c++)
                    gu[prow + c*16] = f2bfu(acc[mr][c][qq]);
            }
        }
    }
#undef LOADB1
#undef STAGEA1
}

/* ---------------- silu: gated = silu(g)*u*router_w ---------------- */
__global__ void silu_k(const unsigned short* __restrict__ gu,
                       const float* __restrict__ pair_w,
                       unsigned short* __restrict__ gated){
    const int t = threadIdx.x;                 // 192 threads, 2 rows/block
    const int r = (t >= 96) ? 1 : 0;
    const int jg = t - r*96;
    const int p = blockIdx.x*2 + r;
    bh8 g8 = *(const bh8*)(gu + (size_t)p*GUF + jg*8);
    bh8 u8 = *(const bh8*)(gu + (size_t)p*GUF + INTER + jg*8);
    float wgt = pair_w[p];
    bh8 o;
#pragma unroll
    for (int j=0;j<8;j++){
        float g = bf2f((unsigned short)g8[j]);
        float u = bf2f((unsigned short)u8[j]);
        float sil = g / (1.f + __expf(-g));
        o[j] = (short)f2bfu(sil*u*wgt);
    }
    *(bh8*)(gated + (size_t)p*INTER + jg*8) = o;
}

/* ============== grouped GEMM2: gated(bf16) x down(f32) -> out (atomic f32) ============== */
__global__ __launch_bounds__(512,4) void gemm2_k(
        const unsigned short* __restrict__ gated, const float* __restrict__ down,
        const int* __restrict__ nmt, const int* __restrict__ te,
        const int* __restrict__ tr0, const int* __restrict__ trn,
        const int* __restrict__ pair_tok, float* __restrict__ out){
    __shared__ __align__(16) unsigned short As[2][BM*32];
    __shared__ __align__(16) unsigned short Bs[2][256*40];
    __shared__ int s_tok[BM];

    TILE_DECODE()
    const int n0 = nt*256;

    const int t = threadIdx.x;
    if (t < BM){
        int p = row0 + t; if (p > NPAIRS-1) p = NPAIRS-1;
        s_tok[t] = pair_tok[p];
    }
    __syncthreads();

    const int w = t>>6, lane = t&63;
    const int l15 = lane & 15, kb = lane >> 4;
    const int wr = w & 3, wc = w >> 2;
    const int sA = (l15>>1)&3;

    const int arow = w*16 + (lane>>2);
    const int ck0 = (lane&3) ^ ((lane>>3)&3);
    int ap = row0 + arow; if (ap > NPAIRS-1) ap = NPAIRS-1;
    const unsigned short* asrc = gated + (size_t)ap*INTER + ck0*8;

    const int cp = t & 127, kh = t >> 7;
    const float* bsrc = down + (size_t)e*INTER*HIDDEN + (size_t)kh*8*HIDDEN + (n0 + 2*cp);
    const unsigned wb0 = (unsigned)((2*cp)*80 + ((kh ^ (cp&3))<<4));

    fx4 acc[2][8];
#pragma unroll
    for (int i=0;i<2;i++)
#pragma unroll
        for (int j=0;j<8;j++) acc[i][j] = (fx4)0.f;

    float2 f0,f1,f2,f3,f4,f5,f6,f7;

#define LOADB2(KS) do{ const float* _bp = bsrc + (size_t)(KS)*BK*HIDDEN;        \
    f0=*(const float2*)(_bp);           f1=*(const float2*)(_bp+HIDDEN);        \
    f2=*(const float2*)(_bp+2*HIDDEN);  f3=*(const float2*)(_bp+3*HIDDEN);      \
    f4=*(const float2*)(_bp+4*HIDDEN);  f5=*(const float2*)(_bp+5*HIDDEN);      \
    f6=*(const float2*)(_bp+6*HIDDEN);  f7=*(const float2*)(_bp+7*HIDDEN); }while(0)

#define STAGEA2(KS,BUF) gload_lds16(asrc + (KS)*BK, &As[BUF][(w*16)*32])

    // prologue
    STAGEA2(0,0); LOADB2(0);
    __syncthreads();
    WRITEB(0);
    __syncthreads();

    for (int k=0;k<NK2;k++){
        const int kn = k+1;
        if (kn < NK2){ LOADB2(kn); STAGEA2(kn, kn&1); }
        COMPUTE(k&1);
        __syncthreads();
        if (kn < NK2) WRITEB(kn&1);
        __syncthreads();
    }

    const int rbase = wr*32 + kb*4;
#pragma unroll
    for (int mr=0;mr<2;mr++){
#pragma unroll
        for (int qq=0;qq<4;qq++){
            int row = rbase + mr*16 + qq;
            if (row < rows){
                float* orow = out + (size_t)s_tok[row]*HIDDEN + n0 + wc*128 + l15;
#pragma unroll
                for (int c=0;c<8;c++)
                    atomicAdd(orow + c*16, acc[mr][c][qq]);
            }
        }
    }
}

/* ---------------- host launch ---------------- */
extern "C" void kernel_launch(void* const* d_in, const int* in_sizes, int n_in,
                              void* d_out, int out_size, void* d_ws, size_t ws_size,
                              hipStream_t stream){
    const float* x    = (const float*)d_in[0];
    const float* gate = (const float*)d_in[1];
    const float* gup  = (const float*)d_in[2];
    const float* down = (const float*)d_in[3];
    float* out = (float*)d_out;
    char*  ws  = (char*)d_ws;

    int*   topk_id  = (int*)  (ws + 0x00000);
    float* topk_w   = (float*)(ws + 0x08000);
    int*   counts   = (int*)  (ws + 0x10000);
    int*   cursors  = (int*)  (ws + 0x10080);
    int*   offs     = (int*)  (ws + 0x10100);
    int*   nmt      = (int*)  (ws + 0x10180);
    int*   te       = (int*)  (ws + 0x10200);
    int*   tr0      = (int*)  (ws + 0x10400);
    int*   trn      = (int*)  (ws + 0x10600);
    int*   pair_tok = (int*)  (ws + 0x10800);
    float* pair_w   = (float*)(ws + 0x18800);
    unsigned short* gated = (unsigned short*)(ws + 0x21000);     // 8192*768*2  = 12.6MB
    unsigned short* xb    = (unsigned short*)(ws + 0xC60000);    // 2048*2048*2 = 8MB
    unsigned short* gu    = (unsigned short*)(ws + 0x1460000);   // 8192*1536*2 = 25.2MB

    hipMemsetAsync(d_out, 0, (size_t)out_size*sizeof(float), stream);
    hipMemsetAsync(counts, 0, NEXPERT*sizeof(int), stream);

    cvt_x_k  <<<T_TOKENS*HIDDEN/(256*8), 256, 0, stream>>>(x, xb);
    router_k <<<T_TOKENS, 64, 0, stream>>>(x, gate, topk_id, topk_w, counts);
    sched_k  <<<1, 64, 0, stream>>>(counts, offs, cursors, nmt, te, tr0, trn);
    scatter_k<<<NPAIRS/256, 256, 0, stream>>>(topk_id, topk_w, cursors, pair_tok, pair_w);
    gemm1_k  <<<MT_MAX*NT1, 512, 0, stream>>>(xb, gup, nmt, te, tr0, trn, pair_tok, gu);
    silu_k   <<<NPAIRS/2, 192, 0, stream>>>(gu, pair_w, gated);
    gemm2_k  <<<MT_MAX*NT2, 512, 0, stream>>>(gated, down, nmt, te, tr0, trn, pair_tok, out);
}

// Round 7
// 490.161 us; speedup vs baseline: 1.0424x; 1.0424x over previous
//
#include <hip/hip_runtime.h>

#define T_TOKENS 2048
#define HIDDEN   2048
#define NEXPERT  32
#define TOPK     4
#define INTER    768
#define GUF      (2*INTER)         /* 1536 */
#define NPAIRS   (T_TOKENS*TOPK)   /* 8192 */
#define BM       256
#define BK       32
#define MT_MAX   63                /* sum ceil(cnt/256) <= 31 + 32 */
#define NT1      6                 /* 1536/256 */
#define NT2      8                 /* 2048/256 */
#define NK1      (HIDDEN/BK)       /* 64 */
#define NK2      (INTER/BK)        /* 24 */

typedef short  bh8 __attribute__((ext_vector_type(8)));   // 8 bf16
typedef float  fx4 __attribute__((ext_vector_type(4)));

#define AS1 __attribute__((address_space(1)))
#define AS3 __attribute__((address_space(3)))

__device__ __forceinline__ void gload_lds16(const void* g, const void* lds_generic){
    __builtin_amdgcn_global_load_lds(
        (const AS1 void*)(unsigned long long)g,
        (AS3 void*)(unsigned int)(unsigned long long)lds_generic,
        16, 0, 0);
}

// pack two f32 -> two bf16 (round-half-up); result shorts [a(lo), b(hi)]
__device__ __forceinline__ unsigned int pack2bf(float a, float b){
    unsigned ua = __float_as_uint(a) + 0x8000u;
    unsigned ub = __float_as_uint(b) + 0x8000u;
    return __builtin_amdgcn_perm(ub, ua, 0x07060302u);
}
__device__ __forceinline__ unsigned short f2bfu(float f){
    return (unsigned short)((__float_as_uint(f) + 0x8000u) >> 16);
}
__device__ __forceinline__ float bf2f(unsigned short s){
    return __uint_as_float(((unsigned)s)<<16);
}

/* ---------------- x -> bf16 ---------------- */
__global__ void cvt_x_k(const float* __restrict__ x, unsigned short* __restrict__ xb){
    int i = (blockIdx.x*256 + threadIdx.x)*8;
    float4 a = *(const float4*)(x+i);
    float4 b = *(const float4*)(x+i+4);
    uint4 o;
    o.x = pack2bf(a.x,a.y); o.y = pack2bf(a.z,a.w);
    o.z = pack2bf(b.x,b.y); o.w = pack2bf(b.z,b.w);
    *(uint4*)(xb+i) = o;
}

/* ---------------- router ---------------- */
__global__ void router_k(const float* __restrict__ x, const float* __restrict__ gate,
                         int* __restrict__ topk_id, float* __restrict__ topk_w,
                         int* __restrict__ counts){
    const int t = blockIdx.x;
    const int l = threadIdx.x;
    const float* xr = x + (size_t)t*HIDDEN;
    float acc[NEXPERT];
#pragma unroll
    for (int e=0;e<NEXPERT;e++) acc[e]=0.f;
    for (int d=l; d<HIDDEN; d+=64){
        float xv = xr[d];
        const float4* g4 = (const float4*)(gate + (size_t)d*NEXPERT);
#pragma unroll
        for (int i=0;i<8;i++){
            float4 g = g4[i];
            acc[i*4+0] += xv*g.x; acc[i*4+1] += xv*g.y;
            acc[i*4+2] += xv*g.z; acc[i*4+3] += xv*g.w;
        }
    }
#pragma unroll
    for (int e=0;e<NEXPERT;e++){
#pragma unroll
        for (int m=1;m<64;m<<=1) acc[e] += __shfl_xor(acc[e], m, 64);
    }
    int ids[TOPK]; float lv[TOPK];
#pragma unroll
    for (int k=0;k<TOPK;k++){
        float m=-1e30f; int mi=0;
#pragma unroll
        for (int e=0;e<NEXPERT;e++){ if (acc[e]>m){ m=acc[e]; mi=e; } }
        ids[k]=mi; lv[k]=m; acc[mi]=-1e30f;
    }
    float ex[TOPK]; float s=0.f;
#pragma unroll
    for (int k=0;k<TOPK;k++){ ex[k]=__expf(lv[k]-lv[0]); s+=ex[k]; }
    if (l==0){
        float inv = 1.f/s;
#pragma unroll
        for (int k=0;k<TOPK;k++){
            topk_id[t*TOPK+k]=ids[k];
            topk_w[t*TOPK+k]=ex[k]*inv;
            atomicAdd(&counts[ids[k]],1);
        }
    }
}

/* ---------------- schedule ---------------- */
__global__ void sched_k(const int* __restrict__ counts, int* __restrict__ offs,
                        int* __restrict__ cursors, int* __restrict__ nmt,
                        int* __restrict__ te, int* __restrict__ tr0, int* __restrict__ trn){
    if (threadIdx.x==0 && blockIdx.x==0){
        int tot=0, nm=0;
        for (int e=0;e<NEXPERT;e++){
            int c = counts[e];
            offs[e]=tot; cursors[e]=tot;
            for (int s=0;s<c;s+=BM){
                te[nm]=e; tr0[nm]=tot+s; trn[nm]=(c-s)<BM?(c-s):BM; nm++;
            }
            tot+=c;
        }
        *nmt = nm;
    }
}

/* ---------------- scatter ---------------- */
__global__ void scatter_k(const int* __restrict__ topk_id, const float* __restrict__ topk_w,
                          int* __restrict__ cursors, int* __restrict__ pair_tok,
                          float* __restrict__ pair_w){
    int g = blockIdx.x*256 + threadIdx.x;
    int e = topk_id[g];
    float w = topk_w[g];
    int pos = atomicAdd(&cursors[e],1);
    pair_tok[pos] = g>>2;
    pair_w[pos]  = w;
}

/* tile-id decode: bijective XCD-chunked swizzle, nt innermost (A-panel L2 reuse) */
#define TILE_DECODE(NTC)                                           \
    const int nwg = gridDim.x;                                     \
    const int q = nwg>>3, r = nwg&7;                               \
    const int xcd = blockIdx.x & 7, bidx = blockIdx.x >> 3;        \
    const int L = (xcd<r ? xcd*(q+1) : r*(q+1)+(xcd-r)*q) + bidx;  \
    const int mt = L / (NTC), nt = L % (NTC);                      \
    if (mt >= *nmt) return;                                        \
    const int e = te[mt], row0 = tr0[mt], rows = trn[mt];

#define MFMA16(A,B,C) __builtin_amdgcn_mfma_f32_16x16x32_bf16(A,B,C,0,0,0)

#define COMPUTE(BUF) do{                                                        \
    const unsigned short* _Ak = As[BUF];                                        \
    const char* _Bb = (const char*)Bs[BUF];                                     \
    bh8 _a0 = *(const bh8*)(_Ak + (wr*64      + l15)*32 + ((kb^sA)<<3));        \
    bh8 _a1 = *(const bh8*)(_Ak + (wr*64 + 16 + l15)*32 + ((kb^sA)<<3));        \
    bh8 _a2 = *(const bh8*)(_Ak + (wr*64 + 32 + l15)*32 + ((kb^sA)<<3));        \
    bh8 _a3 = *(const bh8*)(_Ak + (wr*64 + 48 + l15)*32 + ((kb^sA)<<3));        \
    _Pragma("unroll")                                                           \
    for (int c=0;c<4;c++){                                                      \
        const int bc = wc*64 + c*16 + l15;                                      \
        bh8 _b = *(const bh8*)(_Bb + bc*80 + ((kb ^ ((bc>>3)&3))<<4));          \
        acc[0][c] = MFMA16(_a0,_b,acc[0][c]);                                   \
        acc[1][c] = MFMA16(_a1,_b,acc[1][c]);                                   \
        acc[2][c] = MFMA16(_a2,_b,acc[2][c]);                                   \
        acc[3][c] = MFMA16(_a3,_b,acc[3][c]);                                   \
    } }while(0)

#define WRITEB(BUF) do{ char* _bb = (char*)Bs[BUF];                             \
    *(unsigned*)(_bb + wb      ) = pack2bf(rv0.x, rv1.x);                       \
    *(unsigned*)(_bb + wb +  80) = pack2bf(rv0.y, rv1.y);                       \
    *(unsigned*)(_bb + wb + 160) = pack2bf(rv0.z, rv1.z);                       \
    *(unsigned*)(_bb + wb + 240) = pack2bf(rv0.w, rv1.w); }while(0)

/* ============== grouped GEMM1: xb(bf16) x gup(f32) -> gu(bf16 raw) ==============
   BM=256, BN=256, 1024 thr (16 waves: wr=w&3 64-row group, wc=w>>2 64-col group) */
__global__ __launch_bounds__(1024,4) void gemm1_k(
        const unsigned short* __restrict__ xb, const float* __restrict__ gup,
        const int* __restrict__ nmt, const int* __restrict__ te,
        const int* __restrict__ tr0, const int* __restrict__ trn,
        const int* __restrict__ pair_tok,
        unsigned short* __restrict__ gu){
    __shared__ __align__(16) unsigned short As[2][BM*32];   // 2 x 16KB
    __shared__ __align__(16) unsigned short Bs[2][256*40];  // 2 x 20KB, pitch 80B/col
    __shared__ int s_tok[BM];

    TILE_DECODE(NT1)
    const int n0 = nt*256;

    const int t = threadIdx.x;
    if (t < BM){
        int p = row0 + t; if (p > NPAIRS-1) p = NPAIRS-1;
        s_tok[t] = pair_tok[p];
    }
    __syncthreads();

    const int w = t>>6, lane = t&63;
    const int l15 = lane & 15, kb = lane >> 4;
    const int wr = w & 3, wc = w >> 2;
    const int sA = (l15>>1)&3;

    // A DMA: wave w stages rows w*16..w*16+15 (1 inst/step)
    const int arow = w*16 + (lane>>2);
    const int ck0 = (lane&3) ^ ((lane>>3)&3);
    const unsigned short* asrc = xb + (size_t)s_tok[arow]*HIDDEN + ck0*8;

    // B staging: thread -> 4 cols x 2 k-rows, float4 f32 loads
    const int tlow = t & 63, th = t >> 6;
    const int col4 = tlow*4, bd0 = th*2;
    const int gq = (tlow>>1)&3;
    const unsigned wb = (unsigned)(col4*80 + (((bd0>>3) ^ gq)<<4) + (bd0&7)*2);
    const float* bsrc = gup + (size_t)e*HIDDEN*GUF + (size_t)bd0*GUF + (n0 + col4);

    fx4 acc[4][4];
#pragma unroll
    for (int i=0;i<4;i++)
#pragma unroll
        for (int j=0;j<4;j++) acc[i][j] = (fx4)0.f;

    float4 rv0, rv1;
#define LOADB1(KS) do{ const float* _bp = bsrc + (size_t)(KS)*BK*GUF;           \
    rv0 = *(const float4*)(_bp); rv1 = *(const float4*)(_bp + GUF); }while(0)
#define STAGEA1(KS,BUF) gload_lds16(asrc + (KS)*BK, &As[BUF][(w*16)*32])

    // prologue
    STAGEA1(0,0); LOADB1(0);
    __syncthreads();
    WRITEB(0);
    __syncthreads();

    for (int k=0;k<NK1;k++){
        const int kn = k+1;
        if (kn < NK1){ LOADB1(kn); STAGEA1(kn, kn&1); }
        COMPUTE(k&1);
        __syncthreads();
        if (kn < NK1) WRITEB(kn&1);
        __syncthreads();
    }

    // epilogue: raw gu write (silu in separate pass)
#pragma unroll
    for (int mr=0;mr<4;mr++){
#pragma unroll
        for (int qq=0;qq<4;qq++){
            int row = wr*64 + mr*16 + kb*4 + qq;
            if (row < rows){
                size_t prow = (size_t)(row0 + row)*GUF + n0 + wc*64 + l15;
#pragma unroll
                for (int c=0;c<4;c++)
                    gu[prow + c*16] = f2bfu(acc[mr][c][qq]);
            }
        }
    }
#undef LOADB1
#undef STAGEA1
}

/* ---------------- silu: gated = silu(g)*u*router_w ---------------- */
__global__ void silu_k(const unsigned short* __restrict__ gu,
                       const float* __restrict__ pair_w,
                       unsigned short* __restrict__ gated){
    const int t = threadIdx.x;                 // 192 threads, 2 rows/block
    const int r = (t >= 96) ? 1 : 0;
    const int jg = t - r*96;
    const int p = blockIdx.x*2 + r;
    bh8 g8 = *(const bh8*)(gu + (size_t)p*GUF + jg*8);
    bh8 u8 = *(const bh8*)(gu + (size_t)p*GUF + INTER + jg*8);
    float wgt = pair_w[p];
    bh8 o;
#pragma unroll
    for (int j=0;j<8;j++){
        float g = bf2f((unsigned short)g8[j]);
        float u = bf2f((unsigned short)u8[j]);
        float sil = g / (1.f + __expf(-g));
        o[j] = (short)f2bfu(sil*u*wgt);
    }
    *(bh8*)(gated + (size_t)p*INTER + jg*8) = o;
}

/* ============== grouped GEMM2: gated(bf16) x down(f32) -> out (atomic f32) ============== */
__global__ __launch_bounds__(1024,4) void gemm2_k(
        const unsigned short* __restrict__ gated, const float* __restrict__ down,
        const int* __restrict__ nmt, const int* __restrict__ te,
        const int* __restrict__ tr0, const int* __restrict__ trn,
        const int* __restrict__ pair_tok, float* __restrict__ out){
    __shared__ __align__(16) unsigned short As[2][BM*32];
    __shared__ __align__(16) unsigned short Bs[2][256*40];
    __shared__ int s_tok[BM];

    TILE_DECODE(NT2)
    const int n0 = nt*256;

    const int t = threadIdx.x;
    if (t < BM){
        int p = row0 + t; if (p > NPAIRS-1) p = NPAIRS-1;
        s_tok[t] = pair_tok[p];
    }
    __syncthreads();

    const int w = t>>6, lane = t&63;
    const int l15 = lane & 15, kb = lane >> 4;
    const int wr = w & 3, wc = w >> 2;
    const int sA = (l15>>1)&3;

    const int arow = w*16 + (lane>>2);
    const int ck0 = (lane&3) ^ ((lane>>3)&3);
    int ap = row0 + arow; if (ap > NPAIRS-1) ap = NPAIRS-1;
    const unsigned short* asrc = gated + (size_t)ap*INTER + ck0*8;

    const int tlow = t & 63, th = t >> 6;
    const int col4 = tlow*4, bd0 = th*2;
    const int gq = (tlow>>1)&3;
    const unsigned wb = (unsigned)(col4*80 + (((bd0>>3) ^ gq)<<4) + (bd0&7)*2);
    const float* bsrc = down + (size_t)e*INTER*HIDDEN + (size_t)bd0*HIDDEN + (n0 + col4);

    fx4 acc[4][4];
#pragma unroll
    for (int i=0;i<4;i++)
#pragma unroll
        for (int j=0;j<4;j++) acc[i][j] = (fx4)0.f;

    float4 rv0, rv1;
#define LOADB2(KS) do{ const float* _bp = bsrc + (size_t)(KS)*BK*HIDDEN;        \
    rv0 = *(const float4*)(_bp); rv1 = *(const float4*)(_bp + HIDDEN); }while(0)
#define STAGEA2(KS,BUF) gload_lds16(asrc + (KS)*BK, &As[BUF][(w*16)*32])

    STAGEA2(0,0); LOADB2(0);
    __syncthreads();
    WRITEB(0);
    __syncthreads();

    for (int k=0;k<NK2;k++){
        const int kn = k+1;
        if (kn < NK2){ LOADB2(kn); STAGEA2(kn, kn&1); }
        COMPUTE(k&1);
        __syncthreads();
        if (kn < NK2) WRITEB(kn&1);
        __syncthreads();
    }

#pragma unroll
    for (int mr=0;mr<4;mr++){
#pragma unroll
        for (int qq=0;qq<4;qq++){
            int row = wr*64 + mr*16 + kb*4 + qq;
            if (row < rows){
                float* orow = out + (size_t)s_tok[row]*HIDDEN + n0 + wc*64 + l15;
#pragma unroll
                for (int c=0;c<4;c++)
                    atomicAdd(orow + c*16, acc[mr][c][qq]);
            }
        }
    }
#undef LOADB2
#undef STAGEA2
}

/* ---------------- host launch ---------------- */
extern "C" void kernel_launch(void* const* d_in, const int* in_sizes, int n_in,
                              void* d_out, int out_size, void* d_ws, size_t ws_size,
                              hipStream_t stream){
    const float* x    = (const float*)d_in[0];
    const float* gate = (const float*)d_in[1];
    const float* gup  = (const float*)d_in[2];
    const float* down = (const float*)d_in[3];
    float* out = (float*)d_out;
    char*  ws  = (char*)d_ws;

    int*   topk_id  = (int*)  (ws + 0x00000);
    float* topk_w   = (float*)(ws + 0x08000);
    int*   counts   = (int*)  (ws + 0x10000);
    int*   cursors  = (int*)  (ws + 0x10080);
    int*   offs     = (int*)  (ws + 0x10100);
    int*   nmt      = (int*)  (ws + 0x10180);
    int*   te       = (int*)  (ws + 0x10200);
    int*   tr0      = (int*)  (ws + 0x10400);
    int*   trn      = (int*)  (ws + 0x10600);
    int*   pair_tok = (int*)  (ws + 0x10800);
    float* pair_w   = (float*)(ws + 0x18800);
    unsigned short* gated = (unsigned short*)(ws + 0x21000);     // 8192*768*2  = 12.6MB
    unsigned short* xb    = (unsigned short*)(ws + 0xC60000);    // 2048*2048*2 = 8MB
    unsigned short* gu    = (unsigned short*)(ws + 0x1460000);   // 8192*1536*2 = 25.2MB

    hipMemsetAsync(d_out, 0, (size_t)out_size*sizeof(float), stream);
    hipMemsetAsync(counts, 0, NEXPERT*sizeof(int), stream);

    cvt_x_k  <<<T_TOKENS*HIDDEN/(256*8), 256, 0, stream>>>(x, xb);
    router_k <<<T_TOKENS, 64, 0, stream>>>(x, gate, topk_id, topk_w, counts);
    sched_k  <<<1, 64, 0, stream>>>(counts, offs, cursors, nmt, te, tr0, trn);
    scatter_k<<<NPAIRS/256, 256, 0, stream>>>(topk_id, topk_w, cursors, pair_tok, pair_w);
    gemm1_k  <<<MT_MAX*NT1, 1024, 0, stream>>>(xb, gup, nmt, te, tr0, trn, pair_tok, gu);
    silu_k   <<<NPAIRS/2, 192, 0, stream>>>(gu, pair_w, gated);
    gemm2_k  <<<MT_MAX*NT2, 1024, 0, stream>>>(gated, down, nmt, te, tr0, trn, pair_tok, out);
}